// Round 5
// baseline (141.175 us; speedup 1.0000x reference)
//
#include <hip/hip_runtime.h>

// Problem constants
#define NTOK   32768
#define CDIM   128
#define NH     8
#define QT     32     // rows per k_out block

typedef __bf16 bf16;
typedef __bf16 bf16x4v __attribute__((ext_vector_type(4)));
typedef __bf16 bf16x8v __attribute__((ext_vector_type(8)));
typedef float  f32x4   __attribute__((ext_vector_type(4)));

__device__ __forceinline__ f32x4 mfma16(bf16x8v a, bf16x8v b, f32x4 c) {
  return __builtin_amdgcn_mfma_f32_16x16x32_bf16(a, b, c, 0, 0, 0);
}

__device__ __forceinline__ float xred16(float v) {
  v += __shfl_xor(v, 1);
  v += __shfl_xor(v, 2);
  v += __shfl_xor(v, 4);
  v += __shfl_xor(v, 8);
  return v;
}

// swizzled element index for row-major [R][128] bf16 LDS tiles
__device__ __forceinline__ int sidx(int row, int col) {
  return row * 128 + (col ^ ((row & 7) << 3));
}

// Fragment-tiled global layout: T[h][tile][kk][lane][8];
// element j -> original [16*tile + (lane&15)][32*kk + 8*(lane>>4) + j]
__device__ __forceinline__ int tidx(int h, int tile, int kk, int lane) {
  return (((h * 8 + tile) * 4 + kk) * 64 + lane) * 8;
}

// ---------------------------------------------------------------------------
// k_src: source f32 -> bf16 A-fragment-tiled srcT[rb16][kk][lane][8]
// grid 2048 x 256 (block = one 16-row tile)
// ---------------------------------------------------------------------------
__global__ void __launch_bounds__(256) k_src(
    const float* __restrict__ src, bf16* __restrict__ srcT)
{
  const int rb = blockIdx.x;
  const int tid = threadIdx.x;
  const int row = tid >> 4, col0 = (tid & 15) * 8;
  const float* p = src + (rb * 16 + row) * CDIM + col0;
  f32x4 v0 = *(const f32x4*)p;
  f32x4 v1 = *(const f32x4*)(p + 4);
  bf16x8v o;
  o[0] = (bf16)v0[0]; o[1] = (bf16)v0[1]; o[2] = (bf16)v0[2]; o[3] = (bf16)v0[3];
  o[4] = (bf16)v1[0]; o[5] = (bf16)v1[1]; o[6] = (bf16)v1[2]; o[7] = (bf16)v1[3];
  const int kk = col0 >> 5, lg = (col0 >> 3) & 3;
  const int lane = row + 16 * lg;
  *(bf16x8v*)(srcT + ((rb * 4 + kk) * 64 + lane) * 8) = o;
}

// ---------------------------------------------------------------------------
// k_prep: Wq/Wk/Wv -> bf16 fragment-tiled; Wvs = sum_h Wv; Wvbs = sum_h Wv_b
// ---------------------------------------------------------------------------
__global__ void __launch_bounds__(128) k_prep(
    const float* __restrict__ Wq, const float* __restrict__ Wk,
    const float* __restrict__ Wv, const float* __restrict__ Wv_b,
    bf16* __restrict__ wqT, bf16* __restrict__ wkT, bf16* __restrict__ wvT,
    float* __restrict__ Wvs, float* __restrict__ Wvbs)
{
  const int h = blockIdx.x >> 7, o = blockIdx.x & 127;
  const int i = threadIdx.x;
  const int src = (h * CDIM + o) * CDIM + i;
  const int ot = o >> 4, l15 = o & 15;
  const int kk = i >> 5, lg = (i >> 3) & 3, j = i & 7;
  const int dst = tidx(h, ot, kk, l15 + 16 * lg) + j;
  wqT[dst] = (bf16)Wq[src];
  wkT[dst] = (bf16)Wk[src];
  wvT[dst] = (bf16)Wv[src];
  if (h == 0) {
    float s = 0.f;
#pragma unroll
    for (int hh = 0; hh < NH; ++hh) s += Wv[(hh * CDIM + o) * CDIM + i];
    Wvs[o * CDIM + i] = s;
    if (o == 0) {
      float sb = 0.f;
#pragma unroll
      for (int hh = 0; hh < NH; ++hh) sb += Wv_b[hh * CDIM + i];
      Wvbs[i] = sb;
    }
  }
}

// ---------------------------------------------------------------------------
// k_prep2: w2sT (fragment-tiled) = vmw @ Wvs; b2s[o] = vmw[o].Wvbs + 8*vmb[o]
// ---------------------------------------------------------------------------
__global__ void __launch_bounds__(128) k_prep2(
    const float* __restrict__ vmw, const float* __restrict__ vmb,
    const float* __restrict__ Wvs, const float* __restrict__ Wvbs,
    bf16* __restrict__ w2sT, float* __restrict__ b2s)
{
  const int o = blockIdx.x, i = threadIdx.x;
  __shared__ float s_vm[128];
  __shared__ float s_rd[128];
  s_vm[i] = vmw[o * CDIM + i];
  __syncthreads();
  float acc = 0.f;
  for (int d = 0; d < CDIM; ++d) acc = fmaf(s_vm[d], Wvs[d * CDIM + i], acc);
  const int ot = o >> 4, l15 = o & 15;
  const int kk = i >> 5, lg = (i >> 3) & 3, j = i & 7;
  w2sT[tidx(0, ot, kk, l15 + 16 * lg) + j] = (bf16)acc;
  s_rd[i] = s_vm[i] * Wvbs[i];
  __syncthreads();
  for (int st = 64; st > 0; st >>= 1) {
    if (i < st) s_rd[i] += s_rd[i + st];
    __syncthreads();
  }
  if (i == 0) b2s[o] = s_rd[0] + 8.f * vmb[o];
}

// ---------------------------------------------------------------------------
// k_ktv: per (chunk c, head h): proj GEMMs from srcT (global A-frags),
//        in-register+LDS norms (2 barriers/subtile), ktv + ksum partials.
// grid nchunk*8, 256 threads (4 waves).
// ---------------------------------------------------------------------------
__global__ void __launch_bounds__(256, 2) k_ktv(
    const bf16* __restrict__ srcT,
    const bf16* __restrict__ wkT, const bf16* __restrict__ wvT,
    const float* __restrict__ Wk_b, const float* __restrict__ Wv_b,
    bf16* __restrict__ ktv_part, float* __restrict__ ksum_part, int nsub)
{
  const int h = blockIdx.x & 7, c = blockIdx.x >> 3;
  const int tid = threadIdx.x;
  const int w = tid >> 6, l = tid & 63;
  const int l15 = l & 15, lg = l >> 4;
  const int os = w * 32, owt = os >> 4;

  __shared__ bf16 s_phiT[128][68];     // [m][n]
  __shared__ bf16 s_vT[128][68];       // [d][n]
  __shared__ float s_red2[8][64];      // [w*2+{a2,a4}][row] lane-coalesced
  __shared__ float s_scale[64];

  const f32x4 z4 = {0.f, 0.f, 0.f, 0.f};

  // hoisted loop-invariant weight fragments + biases
  bf16x8v bWk[2][4], bWv[2][4];
  float bK[2], bV[2];
#pragma unroll
  for (int ot = 0; ot < 2; ++ot) {
#pragma unroll
    for (int kk = 0; kk < 4; ++kk) {
      bWk[ot][kk] = *(const bf16x8v*)(wkT + tidx(h, owt + ot, kk, l));
      bWv[ot][kk] = *(const bf16x8v*)(wvT + tidx(h, owt + ot, kk, l));
    }
    bK[ot] = Wk_b[h * CDIM + os + ot * 16 + l15];
    bV[ot] = Wv_b[h * CDIM + os + ot * 16 + l15];
  }

  const int wd = (w >> 1) * 64, wm = (w & 1) * 64;
  f32x4 acc[4][4];
#pragma unroll
  for (int dt = 0; dt < 4; ++dt)
#pragma unroll
    for (int mt = 0; mt < 4; ++mt) acc[dt][mt] = z4;
  float ksacc[2] = {0.f, 0.f};

#pragma unroll 1
  for (int s = 0; s < nsub; ++s) {
    const int rbase = (c * nsub + s) * 4;   // 16-row-block index
    // proj GEMMs: A-frags straight from global tiled srcT (L2-hot)
    f32x4 accK[4][2], accV[4][2];
#pragma unroll
    for (int nt = 0; nt < 4; ++nt)
#pragma unroll
      for (int ot = 0; ot < 2; ++ot) { accK[nt][ot] = z4; accV[nt][ot] = z4; }
#pragma unroll
    for (int kk = 0; kk < 4; ++kk) {
      bf16x8v a[4];
#pragma unroll
      for (int nt = 0; nt < 4; ++nt)
        a[nt] = *(const bf16x8v*)(srcT + (((rbase + nt) * 4 + kk) * 64 + l) * 8);
#pragma unroll
      for (int nt = 0; nt < 4; ++nt)
#pragma unroll
        for (int ot = 0; ot < 2; ++ot) {
          accK[nt][ot] = mfma16(a[nt], bWk[ot][kk], accK[nt][ot]);
          accV[nt][ot] = mfma16(a[nt], bWv[ot][kk], accV[nt][ot]);
        }
    }
    // compress v to bf16 quads now (accV dead after; saves regs)
    bf16x4v vq[4][2];
#pragma unroll
    for (int nt = 0; nt < 4; ++nt)
#pragma unroll
      for (int ot = 0; ot < 2; ++ot)
#pragma unroll
        for (int r = 0; r < 4; ++r)
          vq[nt][ot][r] = (bf16)(accV[nt][ot][r] + bV[ot]);
    // x^2 (no denom scale: cancels in output ratio) + strip norms
#pragma unroll
    for (int nt = 0; nt < 4; ++nt)
#pragma unroll
      for (int r = 0; r < 4; ++r) {
        float a2 = 0.f, a4 = 0.f;
#pragma unroll
        for (int ot = 0; ot < 2; ++ot) {
          float x = fmaxf(accK[nt][ot][r] + bK[ot], 0.f) + 1e-6f;
          float x2 = x * x;
          accK[nt][ot][r] = x2;
          a2 += x2;
          a4 += x2 * x2;
        }
        a2 = xred16(a2);
        a4 = xred16(a4);
        if (l15 == 0) {
          s_red2[w * 2 + 0][nt * 16 + lg * 4 + r] = a2;
          s_red2[w * 2 + 1][nt * 16 + lg * 4 + r] = a4;
        }
      }
    __syncthreads();  // B1
    // wave-redundant scale compute: each wave's 64 lanes cover all rows.
    // same-wave LDS produce->consume needs no barrier.
    {
      float S2 = s_red2[0][l] + s_red2[2][l] + s_red2[4][l] + s_red2[6][l];
      float S4 = s_red2[1][l] + s_red2[3][l] + s_red2[5][l] + s_red2[7][l];
      s_scale[l] = sqrtf(S2) / (sqrtf(S4) + 1e-8f);
    }
    // pack: phi = x2*scale -> s_phiT[m][n], v -> s_vT[d][n]
#pragma unroll
    for (int nt = 0; nt < 4; ++nt) {
      f32x4 sc = *(const f32x4*)&s_scale[nt * 16 + lg * 4];
#pragma unroll
      for (int ot = 0; ot < 2; ++ot) {
        bf16x4v ph;
#pragma unroll
        for (int r = 0; r < 4; ++r) {
          float p = accK[nt][ot][r] * sc[r];
          ksacc[ot] += p;
          ph[r] = (bf16)p;
        }
        const int colb = os + ot * 16 + l15;
        *(bf16x4v*)&s_phiT[colb][nt * 16 + lg * 4] = ph;
        *(bf16x4v*)&s_vT[colb][nt * 16 + lg * 4] = vq[nt][ot];
      }
    }
    __syncthreads();  // B2
    // ktv += v^T phi  (next iteration's B1 orders these reads vs next pack)
#pragma unroll
    for (int kk = 0; kk < 2; ++kk) {
      bf16x8v aV[4], bP[4];
#pragma unroll
      for (int dt = 0; dt < 4; ++dt)
        aV[dt] = *(const bf16x8v*)&s_vT[wd + dt * 16 + l15][kk * 32 + lg * 8];
#pragma unroll
      for (int mt = 0; mt < 4; ++mt)
        bP[mt] = *(const bf16x8v*)&s_phiT[wm + mt * 16 + l15][kk * 32 + lg * 8];
#pragma unroll
      for (int dt = 0; dt < 4; ++dt)
#pragma unroll
        for (int mt = 0; mt < 4; ++mt)
          acc[dt][mt] = mfma16(aV[dt], bP[mt], acc[dt][mt]);
    }
  }

  // ksum partial
#pragma unroll
  for (int ot = 0; ot < 2; ++ot) {
    ksacc[ot] += __shfl_xor(ksacc[ot], 16);
    ksacc[ot] += __shfl_xor(ksacc[ot], 32);
  }
  if (l < 16) {
#pragma unroll
    for (int ot = 0; ot < 2; ++ot)
      ksum_part[(c * NH + h) * CDIM + os + ot * 16 + l] = ksacc[ot];
  }
  // ktv partial store [c][h][d][m]
  bf16* kp = ktv_part + (c * NH + h) * CDIM * CDIM;
#pragma unroll
  for (int dt = 0; dt < 4; ++dt)
#pragma unroll
    for (int mt = 0; mt < 4; ++mt)
#pragma unroll
      for (int r = 0; r < 4; ++r)
        kp[(wd + dt * 16 + lg * 4 + r) * CDIM + wm + mt * 16 + l15] = (bf16)acc[dt][mt][r];
}

// ---------------------------------------------------------------------------
// k_finish: reduce partials -> fragment-tiled ktvT + ksb (T-in-col-0 B-frag)
// grid 576 x 256
// ---------------------------------------------------------------------------
__global__ void __launch_bounds__(256) k_finish(
    const bf16* __restrict__ ktv_part, const float* __restrict__ ksum_part,
    bf16* __restrict__ ktvT, bf16* __restrict__ ksb, int nchunk)
{
  const int b = blockIdx.x;
  if (b < 512) {
    const int t = b * 256 + threadIdx.x;          // < 131072
    const int h = t >> 14;
    const int rem = t & 16383;
    const int d = rem >> 7, m = rem & 127;
    float a = 0.f;
    for (int c = 0; c < nchunk; ++c)
      a += (float)ktv_part[(c * NH + h) * 16384 + (d << 7) + m];
    const int dt = d >> 4, l15 = d & 15;
    const int kk = m >> 5, lg = (m >> 3) & 3, j = m & 7;
    ktvT[tidx(h, dt, kk, l15 + 16 * lg) + j] = (bf16)a;
  } else {
    const int t = (b - 512) * 256 + threadIdx.x;  // < 16384
    const int h = t >> 11;
    const int rem = t & 2047;
    const int kk = rem >> 9, lane = (rem >> 3) & 63, j = rem & 7;
    const int l15 = lane & 15, lg = lane >> 4;
    float a = 0.f;
    if (l15 == 0) {
      const int m = 32 * kk + 8 * lg + j;
      for (int c = 0; c < nchunk; ++c) a += ksum_part[(c * NH + h) * CDIM + m];
    }
    ksb[t] = (bf16)a;
  }
}

// ---------------------------------------------------------------------------
// k_out: per 32-row tile. Per head: prefetch tiled frags -> qs GEMM -> x2 ->
//        dbuf LDS -> num GEMM (+T via ksb) -> accO += num/T. vss from srcT.
// ---------------------------------------------------------------------------
__global__ void __launch_bounds__(256, 2) k_out(
    const float* __restrict__ query, const bf16* __restrict__ srcT,
    const bf16* __restrict__ wqT, const float* __restrict__ Wq_b,
    const bf16* __restrict__ ktvT, const bf16* __restrict__ ksb,
    const bf16* __restrict__ w2sT, const float* __restrict__ b2s,
    float* __restrict__ out)
{
  const int nb = blockIdx.x * QT;
  const int tid = threadIdx.x;
  const int w = tid >> 6, l = tid & 63;
  const int l15 = l & 15, lg = l >> 4;
  const int os = w * 32, owt = os >> 4;

  __shared__ bf16 s_q[QT * 128];      // XOR-swizzled
  __shared__ bf16 s_phi[2][QT * 128]; // double-buffered x2 tile
  __shared__ float s_time[4][QT] __attribute__((aligned(16)));

  const f32x4 z4 = {0.f, 0.f, 0.f, 0.f};

  // stage query (f32 -> bf16, swizzled)
#pragma unroll
  for (int j = 0; j < 4; ++j) {
    const int flat = tid + j * 256;
    const int n = flat >> 5, c4 = (flat & 31) * 4;
    f32x4 vq = *(const f32x4*)(query + (nb + n) * CDIM + c4);
    bf16x4v bq;
    bq[0] = (bf16)vq[0]; bq[1] = (bf16)vq[1]; bq[2] = (bf16)vq[2]; bq[3] = (bf16)vq[3];
    *(bf16x4v*)&s_q[sidx(n, c4)] = bq;
  }

  f32x4 accO[2][2];
#pragma unroll
  for (int nt = 0; nt < 2; ++nt)
#pragma unroll
    for (int ot = 0; ot < 2; ++ot) accO[nt][ot] = z4;

  __syncthreads();

  // hoist q A-frags
  bf16x8v aq[2][4];
#pragma unroll
  for (int nt = 0; nt < 2; ++nt)
#pragma unroll
    for (int kk = 0; kk < 4; ++kk)
      aq[nt][kk] = *(const bf16x8v*)&s_q[sidx(nt * 16 + l15, kk * 32 + lg * 8)];

  for (int h = 0; h < NH; ++h) {
    bf16x8v wf[2][4], kf[2][4], kt[4];
#pragma unroll
    for (int ot = 0; ot < 2; ++ot)
#pragma unroll
      for (int kk = 0; kk < 4; ++kk) {
        wf[ot][kk] = *(const bf16x8v*)(wqT + tidx(h, owt + ot, kk, l));
        kf[ot][kk] = *(const bf16x8v*)(ktvT + tidx(h, owt + ot, kk, l));
      }
#pragma unroll
    for (int kk = 0; kk < 4; ++kk)
      kt[kk] = *(const bf16x8v*)(ksb + ((h * 4 + kk) * 64 + l) * 8);
    float bQ[2];
#pragma unroll
    for (int ot = 0; ot < 2; ++ot) bQ[ot] = Wq_b[h * CDIM + os + ot * 16 + l15];

    // qs GEMM
    f32x4 accQ[2][2];
#pragma unroll
    for (int nt = 0; nt < 2; ++nt)
#pragma unroll
      for (int ot = 0; ot < 2; ++ot) accQ[nt][ot] = z4;
#pragma unroll
    for (int kk = 0; kk < 4; ++kk)
#pragma unroll
      for (int ot = 0; ot < 2; ++ot)
#pragma unroll
        for (int nt = 0; nt < 2; ++nt)
          accQ[nt][ot] = mfma16(aq[nt][kk], wf[ot][kk], accQ[nt][ot]);

    // x2 (scale-free) -> s_phi[h&1]
    bf16* ph = s_phi[h & 1];
#pragma unroll
    for (int nt = 0; nt < 2; ++nt)
#pragma unroll
      for (int ot = 0; ot < 2; ++ot)
#pragma unroll
        for (int r = 0; r < 4; ++r) {
          float x = fmaxf(accQ[nt][ot][r] + bQ[ot], 0.f) + 1e-6f;
          ph[sidx(nt * 16 + lg * 4 + r, os + ot * 16 + l15)] = (bf16)(x * x);
        }
    __syncthreads();  // only barrier in the head loop

    bf16x8v ap[2][4];
#pragma unroll
    for (int nt = 0; nt < 2; ++nt)
#pragma unroll
      for (int kk = 0; kk < 4; ++kk)
        ap[nt][kk] = *(const bf16x8v*)&ph[sidx(nt * 16 + l15, kk * 32 + lg * 8)];

    f32x4 accN[2][2], accT[2];
#pragma unroll
    for (int nt = 0; nt < 2; ++nt) {
      accT[nt] = z4;
#pragma unroll
      for (int dt = 0; dt < 2; ++dt) accN[nt][dt] = z4;
    }
#pragma unroll
    for (int kk = 0; kk < 4; ++kk) {
#pragma unroll
      for (int dt = 0; dt < 2; ++dt)
#pragma unroll
        for (int nt = 0; nt < 2; ++nt)
          accN[nt][dt] = mfma16(ap[nt][kk], kf[dt][kk], accN[nt][dt]);
#pragma unroll
      for (int nt = 0; nt < 2; ++nt)
        accT[nt] = mfma16(ap[nt][kk], kt[kk], accT[nt]);
    }
#pragma unroll
    for (int nt = 0; nt < 2; ++nt)
#pragma unroll
      for (int r = 0; r < 4; ++r) {
        float tr = __shfl(accT[nt][r], l & 48);
        float m = 1.0f / tr;
#pragma unroll
        for (int dt = 0; dt < 2; ++dt)
          accO[nt][dt][r] = fmaf(accN[nt][dt][r], m, accO[nt][dt][r]);
      }
  }

  // fused vss GEMM: A-frags from srcT (same bf16 values as before)
  const int rb0 = blockIdx.x * 2;
#pragma unroll
  for (int kk = 0; kk < 4; ++kk) {
    bf16x8v a[2];
#pragma unroll
    for (int nt = 0; nt < 2; ++nt)
      a[nt] = *(const bf16x8v*)(srcT + (((rb0 + nt) * 4 + kk) * 64 + l) * 8);
#pragma unroll
    for (int ot = 0; ot < 2; ++ot) {
      bf16x8v bw = *(const bf16x8v*)(w2sT + tidx(0, owt + ot, kk, l));
#pragma unroll
      for (int nt = 0; nt < 2; ++nt)
        accO[nt][ot] = mfma16(a[nt], bw, accO[nt][ot]);
    }
  }
  float bb[2];
#pragma unroll
  for (int ot = 0; ot < 2; ++ot) bb[ot] = b2s[os + ot * 16 + l15];

  // mean + time coordinate
  float ps[2][4];
#pragma unroll
  for (int nt = 0; nt < 2; ++nt)
#pragma unroll
    for (int r = 0; r < 4; ++r) ps[nt][r] = 0.f;
#pragma unroll
  for (int nt = 0; nt < 2; ++nt)
#pragma unroll
    for (int ot = 0; ot < 2; ++ot)
#pragma unroll
      for (int r = 0; r < 4; ++r) {
        float v = (accO[nt][ot][r] + bb[ot]) * 0.125f;
        accO[nt][ot][r] = v;
        ps[nt][r] += v * v;
      }
#pragma unroll
  for (int nt = 0; nt < 2; ++nt)
#pragma unroll
    for (int r = 0; r < 4; ++r) {
      float t = xred16(ps[nt][r]);
      if (l15 == 0) s_time[w][nt * 16 + lg * 4 + r] = t;
    }
#pragma unroll
  for (int nt = 0; nt < 2; ++nt)
#pragma unroll
    for (int ot = 0; ot < 2; ++ot)
#pragma unroll
      for (int r = 0; r < 4; ++r)
        out[(nb + nt * 16 + lg * 4 + r) * 129 + 1 + os + ot * 16 + l15] = accO[nt][ot][r];
  __syncthreads();
  if (tid < QT) {
    float S = 1.0f + s_time[0][tid] + s_time[1][tid] + s_time[2][tid] + s_time[3][tid];
    out[(nb + tid) * 129] = sqrtf(S);
  }
}

// ---------------------------------------------------------------------------
extern "C" void kernel_launch(void* const* d_in, const int* in_sizes, int n_in,
                              void* d_out, int out_size, void* d_ws, size_t ws_size,
                              hipStream_t stream) {
  const float* query  = (const float*)d_in[0];
  const float* source = (const float*)d_in[1];
  const float* Wq_w   = (const float*)d_in[2];
  const float* Wq_b   = (const float*)d_in[3];
  const float* Wk_w   = (const float*)d_in[4];
  const float* Wk_b   = (const float*)d_in[5];
  const float* Wv_w   = (const float*)d_in[6];
  const float* Wv_b   = (const float*)d_in[7];
  const float* vmw    = (const float*)d_in[8];
  const float* vmb    = (const float*)d_in[9];

  char* ws = (char*)d_ws;
  bf16*  wqT       = (bf16*)(ws + 0);          // 262144
  bf16*  wkT       = (bf16*)(ws + 262144);     // 262144
  bf16*  wvT       = (bf16*)(ws + 524288);     // 262144
  bf16*  w2sT      = (bf16*)(ws + 786432);     // 32768
  float* b2s       = (float*)(ws + 819200);    // 512
  float* Wvs       = (float*)(ws + 819712);    // 65536
  float* Wvbs      = (float*)(ws + 885248);    // 512
  bf16*  ktvT      = (bf16*)(ws + 885760);     // 262144
  bf16*  ksb       = (bf16*)(ws + 1147904);    // 32768
  bf16*  srcT      = (bf16*)(ws + 1180672);    // 8388608
  float* ksum_part = (float*)(ws + 9569280);   // up to 262144
  bf16*  ktv_part  = (bf16*)(ws + 9831424);    // nchunk*262144

  // pick largest split-K chunk count that fits ws
  int nchunk = 16;
  if (ws_size >= 9831424ull + 64ull * 262144ull) nchunk = 64;
  else if (ws_size >= 9831424ull + 32ull * 262144ull) nchunk = 32;
  const int nsub = (NTOK / 64) / nchunk;

  k_src<<<NTOK / 16, 256, 0, stream>>>(source, srcT);
  k_prep<<<1024, 128, 0, stream>>>(Wq_w, Wk_w, Wv_w, Wv_b, wqT, wkT, wvT, Wvs, Wvbs);
  k_prep2<<<128, 128, 0, stream>>>(vmw, vmb, Wvs, Wvbs, w2sT, b2s);
  k_ktv<<<nchunk * NH, 256, 0, stream>>>(srcT, wkT, wvT, Wk_b, Wv_b, ktv_part, ksum_part, nsub);
  k_finish<<<576, 256, 0, stream>>>(ktv_part, ksum_part, ktvT, ksb, nchunk);
  k_out<<<NTOK / QT, 256, 0, stream>>>(query, srcT, wqT, Wq_b, ktvT, ksb, w2sT, b2s, (float*)d_out);
}